// Round 1
// baseline (598.357 us; speedup 1.0000x reference)
//
#include <hip/hip_runtime.h>

#define TLEN 512
#define BATCH 512
#define HD 128
#define VOC 50000

typedef short bvec8 __attribute__((ext_vector_type(8)));   // 8 bf16 (4 VGPRs) MFMA frag
typedef float fvec4 __attribute__((ext_vector_type(4)));   // MFMA accumulator

__device__ __forceinline__ unsigned short f2bf(float f){
  unsigned u = __builtin_bit_cast(unsigned, f);
  u += 0x7fffu + ((u >> 16) & 1u);          // RNE round to bf16
  return (unsigned short)(u >> 16);
}

__device__ __forceinline__ float fsig(float a){
  return __builtin_amdgcn_rcpf(1.f + __builtin_amdgcn_exp2f(-1.44269504f * a));
}

// ---------------- emb fp32 -> bf16 table ----------------
__global__ void emb_cvt(const float* __restrict__ emb, unsigned short* __restrict__ out, int n4){
  int i = blockIdx.x * blockDim.x + threadIdx.x;
  if (i < n4){
    float4 v = *(const float4*)(emb + (size_t)i * 4);
    ushort4 o;
    o.x = f2bf(v.x); o.y = f2bf(v.y); o.z = f2bf(v.z); o.w = f2bf(v.w);
    *(ushort4*)(out + (size_t)i * 4) = o;
  }
}

// ---------------- persistent bidirectional GRU scan ----------------
// grid: 64 blocks. blocks 0..31 forward (16 batch rows each), 32..63 backward.
// block: 512 threads = 8 waves; wave w owns gate columns [w*16, w*16+16) of each segment.
__global__ __launch_bounds__(512, 2) void gru_scan(
    const int* __restrict__ tokens, const unsigned short* __restrict__ embb,
    const float* __restrict__ Wf, const float* __restrict__ Uf, const float* __restrict__ bfv,
    const float* __restrict__ Wb, const float* __restrict__ Ub, const float* __restrict__ bbv,
    float* __restrict__ hbuf)
{
  const int tid  = threadIdx.x;
  const int wid  = tid >> 6, lane = tid & 63;
  const int l15  = lane & 15, l4 = lane >> 4;
  const int dir  = blockIdx.x >> 5, grp = blockIdx.x & 31;
  const int cw   = wid * 16 + l15;                 // h/gate column in [0,128)

  const float* __restrict__ W  = dir ? Wb : Wf;
  const float* __restrict__ U  = dir ? Ub : Uf;
  const float* __restrict__ bv = dir ? bbv : bfv;

  __shared__ unsigned short hl[16 * 136];          // h state bf16, padded stride 136 (~2-way conflicts)

  // ---- B fragments: stacked [W;U] along K (K=256), bf16, resident in VGPRs ----
  // tile kt covers k in [kt*32, kt*32+32); lane element j -> k = kt*32 + (lane>>4)*8 + j, col = seg + cw
  bvec8 Bz[8], Br[8], Bh[8];
#pragma unroll
  for (int kt = 0; kt < 8; ++kt){
#pragma unroll
    for (int j = 0; j < 8; ++j){
      const int k = kt * 32 + l4 * 8 + j;
      const float* src = (k < 128) ? W : U;
      const int kr = k & 127;
      Bz[kt][j] = (short)f2bf(src[kr * 384 + cw]);
      Br[kt][j] = (short)f2bf(src[kr * 384 + 128 + cw]);
      Bh[kt][j] = (short)f2bf(src[kr * 384 + 256 + cw]);
    }
  }

  // biases: z,r merged (bi+bh); hh halves kept separate (r multiplies recurrent half only)
  const float bzs = bv[cw]       + bv[384 + cw];
  const float brs = bv[128 + cw] + bv[384 + 128 + cw];
  const float bxh = bv[256 + cw];
  const float buh = bv[384 + 256 + cw];

  for (int i = tid; i < 16 * 136; i += 512) hl[i] = 0;
  float h0 = 0.f, h1 = 0.f, h2 = 0.f, h3 = 0.f;    // h[row=l4*4+i][cw] fp32 master copy
  __syncthreads();

  const int  myrow = grp * 16 + l15;               // batch row this lane gathers x for
  const long tb    = (long)myrow * TLEN;
  auto teff = [&](int t){ t = (t > TLEN - 1) ? (TLEN - 1) : t; return dir ? (TLEN - 1 - t) : t; };

  int tok1 = tokens[tb + teff(1)];                 // token for t+1 (ready)
  int tok2 = tokens[tb + teff(2)];                 // token for t+2 (in flight/ready)
  bvec8 xA[4], xB[4];
  {
    int tok0 = tokens[tb + teff(0)];
    const bvec8* p = (const bvec8*)(embb + (size_t)tok0 * HD);
#pragma unroll
    for (int kt = 0; kt < 4; ++kt) xA[kt] = p[kt * 4 + l4];
  }

  auto body = [&](int t, bvec8* cur, bvec8* nxt){
    // prefetch x-frags for t+1 (one full step of latency cover) + token for t+3
    {
      const bvec8* p = (const bvec8*)(embb + (size_t)tok1 * HD);
#pragma unroll
      for (int kt = 0; kt < 4; ++kt) nxt[kt] = p[kt * 4 + l4];
    }
    tok1 = tok2;
    tok2 = tokens[tb + teff(t + 3)];

    // h fragments from LDS (written by all waves at end of previous step)
    bvec8 hf[4];
#pragma unroll
    for (int kt = 0; kt < 4; ++kt)
      hf[kt] = *(const bvec8*)&hl[l15 * 136 + kt * 32 + l4 * 8];

    fvec4 aZ = {bzs, bzs, bzs, bzs};
    fvec4 aR = {brs, brs, brs, brs};
    fvec4 aX = {bxh, bxh, bxh, bxh};
    fvec4 aU = {buh, buh, buh, buh};
#pragma unroll
    for (int kt = 0; kt < 4; ++kt){                // x part: k 0..127
      aZ = __builtin_amdgcn_mfma_f32_16x16x32_bf16(cur[kt], Bz[kt], aZ, 0, 0, 0);
      aR = __builtin_amdgcn_mfma_f32_16x16x32_bf16(cur[kt], Br[kt], aR, 0, 0, 0);
      aX = __builtin_amdgcn_mfma_f32_16x16x32_bf16(cur[kt], Bh[kt], aX, 0, 0, 0);
    }
#pragma unroll
    for (int kt = 0; kt < 4; ++kt){                // h part: k 128..255
      aZ = __builtin_amdgcn_mfma_f32_16x16x32_bf16(hf[kt], Bz[kt + 4], aZ, 0, 0, 0);
      aR = __builtin_amdgcn_mfma_f32_16x16x32_bf16(hf[kt], Br[kt + 4], aR, 0, 0, 0);
      aU = __builtin_amdgcn_mfma_f32_16x16x32_bf16(hf[kt], Bh[kt + 4], aU, 0, 0, 0);
    }

    // gates (rows l4*4+i, column cw): z=sig, r=sig, hh=tanh(xh + r*uh), h = z*h + (1-z)*hh
    unsigned short w0, w1, w2, w3;
#define GATE(i, hh) { \
      float zz = fsig(aZ[i]); float rg = fsig(aR[i]); \
      float ar = aX[i] + rg * aU[i]; ar = fmaxf(ar, -30.f); \
      float y  = __builtin_amdgcn_exp2f(-2.88539008f * ar); \
      float th = (1.f - y) * __builtin_amdgcn_rcpf(1.f + y); \
      hh = th + zz * (hh - th); }
    GATE(0, h0) GATE(1, h1) GATE(2, h2) GATE(3, h3)
#undef GATE
    w0 = f2bf(h0); w1 = f2bf(h1); w2 = f2bf(h2); w3 = f2bf(h3);

    // raw barriers: drain LDS only (lgkmcnt), keep global prefetch loads in flight (no vmcnt drain)
    asm volatile("s_waitcnt lgkmcnt(0)" ::: "memory");
    __builtin_amdgcn_s_barrier();                   // all reads of h done
    const int wb = (l4 * 4) * 136 + cw;
    hl[wb] = w0; hl[wb + 136] = w1; hl[wb + 272] = w2; hl[wb + 408] = w3;
    asm volatile("s_waitcnt lgkmcnt(0)" ::: "memory");
    __builtin_amdgcn_s_barrier();                   // new h visible
  };

  for (int t = 0; t < TLEN; t += 2){
    body(t,     xA, xB);
    body(t + 1, xB, xA);
  }

  // final state -> hbuf[512][256], fwd cols 0..127, bwd cols 128..255
  float* hout = hbuf + (size_t)(grp * 16 + l4 * 4) * 256 + dir * 128 + cw;
  hout[0] = h0; hout[256] = h1; hout[512] = h2; hout[768] = h3;
}

// ---------------- head: sigmoid(hcat @ Wd + bd) ----------------
__global__ void head_k(const float* __restrict__ hbuf, const float* __restrict__ Wd,
                       const float* __restrict__ bd, float* __restrict__ out){
  const int wid = threadIdx.x >> 6, lane = threadIdx.x & 63;
  const int b = blockIdx.x * 4 + wid;
  const float* hr = hbuf + (size_t)b * 256;
  float s = 0.f;
#pragma unroll
  for (int j = 0; j < 4; ++j){ const int k = j * 64 + lane; s += hr[k] * Wd[k]; }
#pragma unroll
  for (int off = 32; off > 0; off >>= 1) s += __shfl_down(s, off);
  if (lane == 0) out[b] = 1.f / (1.f + __expf(-(s + bd[0])));
}

extern "C" void kernel_launch(void* const* d_in, const int* in_sizes, int n_in,
                              void* d_out, int out_size, void* d_ws, size_t ws_size,
                              hipStream_t stream){
  const int*   tokens = (const int*)  d_in[0];
  const float* emb    = (const float*)d_in[1];
  const float* Wf     = (const float*)d_in[2];
  const float* Uf     = (const float*)d_in[3];
  const float* bf_    = (const float*)d_in[4];
  const float* Wb     = (const float*)d_in[5];
  const float* Ub     = (const float*)d_in[6];
  const float* bb_    = (const float*)d_in[7];
  const float* Wd     = (const float*)d_in[8];
  const float* bd     = (const float*)d_in[9];
  float* out = (float*)d_out;

  unsigned short* embb = (unsigned short*)d_ws;                       // 12.8 MB bf16 table
  float* hbuf = (float*)((char*)d_ws + (size_t)VOC * HD * sizeof(unsigned short)); // 512 KB

  const int n4 = VOC * HD / 4;
  emb_cvt<<<(n4 + 255) / 256, 256, 0, stream>>>(emb, embb, n4);
  gru_scan<<<64, 512, 0, stream>>>(tokens, embb, Wf, Uf, bf_, Wb, Ub, bb_, hbuf);
  head_k<<<BATCH / 4, 256, 0, stream>>>(hbuf, Wd, bd, out);
}

// Round 2
// 376.660 us; speedup vs baseline: 1.5886x; 1.5886x over previous
//
#include <hip/hip_runtime.h>

#define TLEN 512
#define BATCH 512
#define HD 128
#define VOC 50000

typedef short bvec8 __attribute__((ext_vector_type(8)));   // 8 bf16 (4 VGPRs) MFMA frag
typedef float fvec4 __attribute__((ext_vector_type(4)));   // MFMA accumulator

__device__ __forceinline__ unsigned short f2bf(float f){
  unsigned u = __builtin_bit_cast(unsigned, f);
  u += 0x7fffu + ((u >> 16) & 1u);          // RNE round to bf16
  return (unsigned short)(u >> 16);
}

__device__ __forceinline__ float fsig(float a){
  return __builtin_amdgcn_rcpf(1.f + __builtin_amdgcn_exp2f(-1.44269504f * a));
}

// ---------------- emb fp32 -> bf16 table ----------------
__global__ void emb_cvt(const float* __restrict__ emb, unsigned short* __restrict__ out, int n4){
  int i = blockIdx.x * blockDim.x + threadIdx.x;
  if (i < n4){
    float4 v = *(const float4*)(emb + (size_t)i * 4);
    ushort4 o;
    o.x = f2bf(v.x); o.y = f2bf(v.y); o.z = f2bf(v.z); o.w = f2bf(v.w);
    *(ushort4*)(out + (size_t)i * 4) = o;
  }
}

// ---------------- persistent bidirectional GRU scan, R=4 rows/block ----------------
// grid: 256 blocks. blocks 0..127 forward (4 batch rows each), 128..255 backward.
// batch rows sit at MFMA tile rows {0,4,8,12} -> each lane's acc reg 0 is a valid gate.
// block: 512 threads = 8 waves; wave w owns gate columns [w*16, w*16+16) of each segment.
__global__ __launch_bounds__(512, 2) void gru_scan(
    const int* __restrict__ tokens, const unsigned short* __restrict__ embb,
    const float* __restrict__ Wf, const float* __restrict__ Uf, const float* __restrict__ bfv,
    const float* __restrict__ Wb, const float* __restrict__ Ub, const float* __restrict__ bbv,
    float* __restrict__ hbuf)
{
  const int tid  = threadIdx.x;
  const int wid  = tid >> 6, lane = tid & 63;
  const int l15  = lane & 15, l4 = lane >> 4;
  const int dir  = blockIdx.x >> 7, grp = blockIdx.x & 127;
  const int cw   = wid * 16 + l15;                 // h/gate column in [0,128)

  const float* __restrict__ W  = dir ? Wb : Wf;
  const float* __restrict__ U  = dir ? Ub : Uf;
  const float* __restrict__ bv = dir ? bbv : bfv;

  // 96 KB LDS -> at most 1 block/CU (no straggler CUs). Two h buffers:
  // elements [0, 16*136) and [4096, 4096+16*136), byte-toggle via elem ^0x1000.
  __shared__ unsigned short hl[49152];

  // ---- B fragments: stacked [W;U] along K (K=256), bf16, resident in VGPRs ----
  bvec8 Bz[8], Br[8], Bh[8];
#pragma unroll
  for (int kt = 0; kt < 8; ++kt){
#pragma unroll
    for (int j = 0; j < 8; ++j){
      const int k = kt * 32 + l4 * 8 + j;
      const float* src = (k < 128) ? W : U;
      const int kr = k & 127;
      Bz[kt][j] = (short)f2bf(src[kr * 384 + cw]);
      Br[kt][j] = (short)f2bf(src[kr * 384 + 128 + cw]);
      Bh[kt][j] = (short)f2bf(src[kr * 384 + 256 + cw]);
    }
  }

  const float bzs = bv[cw]       + bv[384 + cw];
  const float brs = bv[128 + cw] + bv[384 + 128 + cw];
  const float bxh = bv[256 + cw];
  const float buh = bv[384 + 256 + cw];

  for (int i = tid; i < 8192; i += 512) hl[i] = 0;   // both buffers (incl. garbage rows)
  float h0 = 0.f;                                     // h[row=4*l4][cw] fp32 master copy
  __syncthreads();

  // x gather: tile row l15 uses batch row grp*4 + (l15>>2)  (rows duplicated 4x, same lines)
  const long tbx = (long)(grp * 4 + (l15 >> 2)) * TLEN;
  auto teff = [&](int t){ t = (t > TLEN - 1) ? (TLEN - 1) : t; return dir ? (TLEN - 1 - t) : t; };

  bvec8 xA[4], xB[4];
  {
    const bvec8* p0 = (const bvec8*)(embb + (size_t)tokens[tbx + teff(0)] * HD);
    const bvec8* p1 = (const bvec8*)(embb + (size_t)tokens[tbx + teff(1)] * HD);
#pragma unroll
    for (int kt = 0; kt < 4; ++kt){ xA[kt] = p0[kt * 4 + l4]; xB[kt] = p1[kt * 4 + l4]; }
  }
  int tok2 = tokens[tbx + teff(2)];                  // token for next x prefetch

  int p = 0;                                          // current read buffer (elem offset)

  auto body = [&](int t, bvec8* cur){
    // start h-fragment read early (latency hides under x-MFMAs)
    bvec8 hf[4];
#pragma unroll
    for (int kt = 0; kt < 4; ++kt)
      hf[kt] = *(const bvec8*)&hl[p + l15 * 136 + kt * 32 + l4 * 8];

    fvec4 aZ = {bzs, bzs, bzs, bzs};
    fvec4 aR = {brs, brs, brs, brs};
    fvec4 aX = {bxh, bxh, bxh, bxh};
    fvec4 aU = {buh, buh, buh, buh};
#pragma unroll
    for (int kt = 0; kt < 4; ++kt){                   // x part: k 0..127
      aZ = __builtin_amdgcn_mfma_f32_16x16x32_bf16(cur[kt], Bz[kt], aZ, 0, 0, 0);
      aR = __builtin_amdgcn_mfma_f32_16x16x32_bf16(cur[kt], Br[kt], aR, 0, 0, 0);
      aX = __builtin_amdgcn_mfma_f32_16x16x32_bf16(cur[kt], Bh[kt], aX, 0, 0, 0);
    }
    // prefetch x(t+2) into the buffer just consumed (distance-2 ping-pong)
    {
      const bvec8* pn = (const bvec8*)(embb + (size_t)tok2 * HD);
#pragma unroll
      for (int kt = 0; kt < 4; ++kt) cur[kt] = pn[kt * 4 + l4];
      tok2 = tokens[tbx + teff(t + 3)];
    }
#pragma unroll
    for (int kt = 0; kt < 4; ++kt){                   // h part: k 128..255
      aZ = __builtin_amdgcn_mfma_f32_16x16x32_bf16(hf[kt], Bz[kt + 4], aZ, 0, 0, 0);
      aR = __builtin_amdgcn_mfma_f32_16x16x32_bf16(hf[kt], Br[kt + 4], aR, 0, 0, 0);
      aU = __builtin_amdgcn_mfma_f32_16x16x32_bf16(hf[kt], Bh[kt + 4], aU, 0, 0, 0);
    }

    // single gate per lane: row 4*l4 (= batch grp*4 + l4), col cw  (acc reg 0)
    {
      float zz = fsig(aZ[0]);
      float rg = fsig(aR[0]);
      float ar = aX[0] + rg * aU[0]; ar = fmaxf(ar, -30.f);
      float y  = __builtin_amdgcn_exp2f(-2.88539008f * ar);
      float th = (1.f - y) * __builtin_amdgcn_rcpf(1.f + y);
      h0 = th + zz * (h0 - th);
    }
    hl[(p ^ 4096) + (4 * l4) * 136 + cw] = f2bf(h0);

    // one barrier per step: drain LDS (keep global prefetch loads in flight)
    asm volatile("s_waitcnt lgkmcnt(0)" ::: "memory");
    __builtin_amdgcn_s_barrier();
    p ^= 4096;
  };

  for (int t = 0; t < TLEN; t += 2){
    body(t,     xA);
    body(t + 1, xB);
  }

  // final state -> hbuf[512][256], fwd cols 0..127, bwd cols 128..255
  hbuf[(size_t)(grp * 4 + l4) * 256 + dir * 128 + cw] = h0;
}

// ---------------- head: sigmoid(hcat @ Wd + bd) ----------------
__global__ void head_k(const float* __restrict__ hbuf, const float* __restrict__ Wd,
                       const float* __restrict__ bd, float* __restrict__ out){
  const int wid = threadIdx.x >> 6, lane = threadIdx.x & 63;
  const int b = blockIdx.x * 4 + wid;
  const float* hr = hbuf + (size_t)b * 256;
  float s = 0.f;
#pragma unroll
  for (int j = 0; j < 4; ++j){ const int k = j * 64 + lane; s += hr[k] * Wd[k]; }
#pragma unroll
  for (int off = 32; off > 0; off >>= 1) s += __shfl_down(s, off);
  if (lane == 0) out[b] = 1.f / (1.f + __expf(-(s + bd[0])));
}

extern "C" void kernel_launch(void* const* d_in, const int* in_sizes, int n_in,
                              void* d_out, int out_size, void* d_ws, size_t ws_size,
                              hipStream_t stream){
  const int*   tokens = (const int*)  d_in[0];
  const float* emb    = (const float*)d_in[1];
  const float* Wf     = (const float*)d_in[2];
  const float* Uf     = (const float*)d_in[3];
  const float* bf_    = (const float*)d_in[4];
  const float* Wb     = (const float*)d_in[5];
  const float* Ub     = (const float*)d_in[6];
  const float* bb_    = (const float*)d_in[7];
  const float* Wd     = (const float*)d_in[8];
  const float* bd     = (const float*)d_in[9];
  float* out = (float*)d_out;

  unsigned short* embb = (unsigned short*)d_ws;                       // 12.8 MB bf16 table
  float* hbuf = (float*)((char*)d_ws + (size_t)VOC * HD * sizeof(unsigned short)); // 512 KB

  const int n4 = VOC * HD / 4;
  emb_cvt<<<(n4 + 255) / 256, 256, 0, stream>>>(emb, embb, n4);
  gru_scan<<<256, 512, 0, stream>>>(tokens, embb, Wf, Uf, bf_, Wb, Ub, bb_, hbuf);
  head_k<<<BATCH / 4, 256, 0, stream>>>(hbuf, Wd, bd, out);
}

// Round 3
// 257.507 us; speedup vs baseline: 2.3237x; 1.4627x over previous
//
#include <hip/hip_runtime.h>

#define TLEN 512
#define HD 128
#define VOC 50000

typedef short bvec8 __attribute__((ext_vector_type(8)));   // 8 bf16 (4 VGPRs) MFMA frag
typedef float fvec4 __attribute__((ext_vector_type(4)));   // MFMA accumulator

__device__ __forceinline__ unsigned short f2bf(float f){
  unsigned u = __builtin_bit_cast(unsigned, f);
  u += 0x7fffu + ((u >> 16) & 1u);          // RNE round to bf16
  return (unsigned short)(u >> 16);
}

__device__ __forceinline__ float fsig(float a){
  return __builtin_amdgcn_rcpf(1.f + __builtin_amdgcn_exp2f(-1.44269504f * a));
}

// ---------------- emb fp32 -> bf16 table ----------------
__global__ void emb_cvt(const float* __restrict__ emb, unsigned short* __restrict__ out, int n4){
  int i = blockIdx.x * blockDim.x + threadIdx.x;
  if (i < n4){
    float4 v = *(const float4*)(emb + (size_t)i * 4);
    ushort4 o;
    o.x = f2bf(v.x); o.y = f2bf(v.y); o.z = f2bf(v.z); o.w = f2bf(v.w);
    *(ushort4*)(out + (size_t)i * 4) = o;
  }
}

// ---------------- persistent bidirectional GRU scan ----------------
// 256 blocks: 0..127 fwd, 128..255 bwd; 4 batch rows each; 8 waves.
// x-projection packed 4 timesteps/tile: A-row = batch*4 + step_in_group, so
// lane (l4,l15) holds xp[batch l4][t..t+3] in its 4 acc regs -- the same lane
// that owns the recurrent acc reg 0 (h rows at tile rows {0,4,8,12}).
// Per step per wave: 12 recurrent MFMAs + 3 woven next-group xp MFMAs.
__global__ __launch_bounds__(512, 2) void gru_scan(
    const int* __restrict__ tokens, const unsigned short* __restrict__ embb,
    const float* __restrict__ Wf, const float* __restrict__ Uf, const float* __restrict__ bfv,
    const float* __restrict__ Wb, const float* __restrict__ Ub, const float* __restrict__ bbv,
    float* __restrict__ hbuf)
{
  const int tid  = threadIdx.x;
  const int wid  = tid >> 6, lane = tid & 63;
  const int l15  = lane & 15, l4 = lane >> 4;
  const int dir  = blockIdx.x >> 7, grp = blockIdx.x & 127;
  const int cw   = wid * 16 + l15;                 // gate column in [0,128)

  const float* __restrict__ W  = dir ? Wb : Wf;
  const float* __restrict__ U  = dir ? Ub : Uf;
  const float* __restrict__ bv = dir ? bbv : bfv;

  // 96 KB -> 1 block/CU. Two h buffers at elem 0 and 4096 (rows stride 136).
  __shared__ unsigned short hl[49152];

  // B fragments: stacked [W;U] (K=256) bf16 in VGPRs. kt<4 = W, kt>=4 = U.
  bvec8 Bz[8], Br[8], Bh[8];
#pragma unroll
  for (int kt = 0; kt < 8; ++kt){
#pragma unroll
    for (int j = 0; j < 8; ++j){
      const int k = kt * 32 + l4 * 8 + j;
      const float* src = (k < 128) ? W : U;
      const int kr = k & 127;
      Bz[kt][j] = (short)f2bf(src[kr * 384 + cw]);
      Br[kt][j] = (short)f2bf(src[kr * 384 + 128 + cw]);
      Bh[kt][j] = (short)f2bf(src[kr * 384 + 256 + cw]);
    }
  }

  const float biz = bv[cw],       bir = bv[128 + cw],       bix = bv[256 + cw];
  const float bhz = bv[384 + cw], bhr = bv[384 + 128 + cw], bhu = bv[384 + 256 + cw];

  for (int i = tid; i < 8192; i += 512) hl[i] = 0;
  float h0 = 0.f;                                   // h[batch l4][cw]

  // x gather: A-row l15 -> (batch = l15>>2, step-in-group = l15&3)
  const int  brow = l15 >> 2, srow = l15 & 3;
  const long tbx  = (long)(grp * 4 + brow) * TLEN;
  const int  tb0  = dir ? (TLEN - 1) : 0, tsg = dir ? -1 : 1;
  auto tix = [&](int t){ t = (t > TLEN - 1) ? (TLEN - 1) : t; return tb0 + tsg * t; };

  bvec8 xA[4], xB[4];
  fvec4 xZ = {biz, biz, biz, biz}, xR = {bir, bir, bir, bir}, xX = {bix, bix, bix, bix};
  fvec4 nZ, nR, nX;
  {
    // group 0 xp (computed up front), group 1 frags into xA
    const bvec8* p0 = (const bvec8*)(embb + (size_t)tokens[tbx + tix(srow)] * HD);
#pragma unroll
    for (int kt = 0; kt < 4; ++kt) xB[kt] = p0[kt * 4 + l4];
#pragma unroll
    for (int kt = 0; kt < 4; ++kt){
      xZ = __builtin_amdgcn_mfma_f32_16x16x32_bf16(xB[kt], Bz[kt], xZ, 0, 0, 0);
      xR = __builtin_amdgcn_mfma_f32_16x16x32_bf16(xB[kt], Br[kt], xR, 0, 0, 0);
      xX = __builtin_amdgcn_mfma_f32_16x16x32_bf16(xB[kt], Bh[kt], xX, 0, 0, 0);
    }
    const bvec8* p1 = (const bvec8*)(embb + (size_t)tokens[tbx + tix(4 + srow)] * HD);
#pragma unroll
    for (int kt = 0; kt < 4; ++kt) xA[kt] = p1[kt * 4 + l4];
  }
  int tok2 = tokens[tbx + tix(8 + srow)];           // token for frags 2 groups ahead
  nZ = (fvec4){biz, biz, biz, biz}; nR = (fvec4){bir, bir, bir, bir}; nX = (fvec4){bix, bix, bix, bix};

  const int hrd = l15 * 136 + l4 * 8;               // ds_read base (elem)
  const int wb  = (4 * l4) * 136 + cw;              // ds_write slot (elem)
  __syncthreads();

  // One step: read h, weave 3 next-group xp MFMAs (fills lgkm shadow),
  // 12 recurrent MFMAs, gate on acc reg 0, write h, one barrier.
#define STEP(S, P, XF) { \
    bvec8 hf0 = *(const bvec8*)&hl[(P) + hrd +  0]; \
    bvec8 hf1 = *(const bvec8*)&hl[(P) + hrd + 32]; \
    bvec8 hf2 = *(const bvec8*)&hl[(P) + hrd + 64]; \
    bvec8 hf3 = *(const bvec8*)&hl[(P) + hrd + 96]; \
    nZ = __builtin_amdgcn_mfma_f32_16x16x32_bf16(XF[S], Bz[S], nZ, 0, 0, 0); \
    nR = __builtin_amdgcn_mfma_f32_16x16x32_bf16(XF[S], Br[S], nR, 0, 0, 0); \
    nX = __builtin_amdgcn_mfma_f32_16x16x32_bf16(XF[S], Bh[S], nX, 0, 0, 0); \
    fvec4 aZ = {bhz, bhz, bhz, bhz}; fvec4 aR = {bhr, bhr, bhr, bhr}; fvec4 aU = {bhu, bhu, bhu, bhu}; \
    aZ = __builtin_amdgcn_mfma_f32_16x16x32_bf16(hf0, Bz[4], aZ, 0, 0, 0); \
    aR = __builtin_amdgcn_mfma_f32_16x16x32_bf16(hf0, Br[4], aR, 0, 0, 0); \
    aU = __builtin_amdgcn_mfma_f32_16x16x32_bf16(hf0, Bh[4], aU, 0, 0, 0); \
    aZ = __builtin_amdgcn_mfma_f32_16x16x32_bf16(hf1, Bz[5], aZ, 0, 0, 0); \
    aR = __builtin_amdgcn_mfma_f32_16x16x32_bf16(hf1, Br[5], aR, 0, 0, 0); \
    aU = __builtin_amdgcn_mfma_f32_16x16x32_bf16(hf1, Bh[5], aU, 0, 0, 0); \
    aZ = __builtin_amdgcn_mfma_f32_16x16x32_bf16(hf2, Bz[6], aZ, 0, 0, 0); \
    aR = __builtin_amdgcn_mfma_f32_16x16x32_bf16(hf2, Br[6], aR, 0, 0, 0); \
    aU = __builtin_amdgcn_mfma_f32_16x16x32_bf16(hf2, Bh[6], aU, 0, 0, 0); \
    aZ = __builtin_amdgcn_mfma_f32_16x16x32_bf16(hf3, Bz[7], aZ, 0, 0, 0); \
    aR = __builtin_amdgcn_mfma_f32_16x16x32_bf16(hf3, Br[7], aR, 0, 0, 0); \
    aU = __builtin_amdgcn_mfma_f32_16x16x32_bf16(hf3, Bh[7], aU, 0, 0, 0); \
    float zz = fsig(xZ[S] + aZ[0]); \
    float rg = fsig(xR[S] + aR[0]); \
    float ar = xX[S] + rg * aU[0]; ar = fmaxf(ar, -30.f); \
    float y  = __builtin_amdgcn_exp2f(-2.88539008f * ar); \
    float th = (1.f - y) * __builtin_amdgcn_rcpf(1.f + y); \
    h0 = th + zz * (h0 - th); \
    hl[((P) ^ 4096) + wb] = f2bf(h0); \
    asm volatile("s_waitcnt lgkmcnt(0)" ::: "memory"); \
    __builtin_amdgcn_s_barrier(); \
  }

  for (int g = 0; g < 128; g += 2){
    {   // frags for group g+2 -> xB (consumed next odd group)
      const bvec8* pn = (const bvec8*)(embb + (size_t)tok2 * HD);
#pragma unroll
      for (int kt = 0; kt < 4; ++kt) xB[kt] = pn[kt * 4 + l4];
      tok2 = tokens[tbx + tix(4 * (g + 3) + srow)];
    }
    STEP(0, 0, xA) STEP(1, 4096, xA) STEP(2, 0, xA) STEP(3, 4096, xA)
    xZ = nZ; xR = nR; xX = nX;
    nZ = (fvec4){biz, biz, biz, biz}; nR = (fvec4){bir, bir, bir, bir}; nX = (fvec4){bix, bix, bix, bix};
    {   // frags for group g+3 -> xA (consumed next even group)
      const bvec8* pn = (const bvec8*)(embb + (size_t)tok2 * HD);
#pragma unroll
      for (int kt = 0; kt < 4; ++kt) xA[kt] = pn[kt * 4 + l4];
      tok2 = tokens[tbx + tix(4 * (g + 4) + srow)];
    }
    STEP(0, 0, xB) STEP(1, 4096, xB) STEP(2, 0, xB) STEP(3, 4096, xB)
    xZ = nZ; xR = nR; xX = nX;
    nZ = (fvec4){biz, biz, biz, biz}; nR = (fvec4){bir, bir, bir, bir}; nX = (fvec4){bix, bix, bix, bix};
  }
#undef STEP

  // final state -> hbuf[512][256], fwd cols 0..127, bwd cols 128..255
  hbuf[(size_t)(grp * 4 + l4) * 256 + dir * 128 + cw] = h0;
}

// ---------------- head: sigmoid(hcat @ Wd + bd) ----------------
__global__ void head_k(const float* __restrict__ hbuf, const float* __restrict__ Wd,
                       const float* __restrict__ bd, float* __restrict__ out){
  const int wid = threadIdx.x >> 6, lane = threadIdx.x & 63;
  const int b = blockIdx.x * 4 + wid;
  const float* hr = hbuf + (size_t)b * 256;
  float s = 0.f;
#pragma unroll
  for (int j = 0; j < 4; ++j){ const int k = j * 64 + lane; s += hr[k] * Wd[k]; }
#pragma unroll
  for (int off = 32; off > 0; off >>= 1) s += __shfl_down(s, off);
  if (lane == 0) out[b] = 1.f / (1.f + __expf(-(s + bd[0])));
}

extern "C" void kernel_launch(void* const* d_in, const int* in_sizes, int n_in,
                              void* d_out, int out_size, void* d_ws, size_t ws_size,
                              hipStream_t stream){
  const int*   tokens = (const int*)  d_in[0];
  const float* emb    = (const float*)d_in[1];
  const float* Wf     = (const float*)d_in[2];
  const float* Uf     = (const float*)d_in[3];
  const float* bf_    = (const float*)d_in[4];
  const float* Wb     = (const float*)d_in[5];
  const float* Ub     = (const float*)d_in[6];
  const float* bb_    = (const float*)d_in[7];
  const float* Wd     = (const float*)d_in[8];
  const float* bd     = (const float*)d_in[9];
  float* out = (float*)d_out;

  unsigned short* embb = (unsigned short*)d_ws;                       // 12.8 MB bf16 table
  float* hbuf = (float*)((char*)d_ws + (size_t)VOC * HD * sizeof(unsigned short)); // 512 KB

  const int n4 = VOC * HD / 4;
  emb_cvt<<<(n4 + 255) / 256, 256, 0, stream>>>(emb, embb, n4);
  gru_scan<<<256, 512, 0, stream>>>(tokens, embb, Wf, Uf, bf_, Wb, Ub, bb_, hbuf);
  head_k<<<128, 256, 0, stream>>>(hbuf, Wd, bd, out);
}

// Round 4
// 248.928 us; speedup vs baseline: 2.4037x; 1.0345x over previous
//
#include <hip/hip_runtime.h>

#define TLEN 512
#define HD 128
#define VOC 50000

typedef short bvec8 __attribute__((ext_vector_type(8)));   // 8 bf16 (4 VGPRs)
typedef float fvec4 __attribute__((ext_vector_type(4)));   // f32 MFMA accumulator
typedef int   ivec4 __attribute__((ext_vector_type(4)));   // 16B LDS read
typedef int   ivec8 __attribute__((ext_vector_type(8)));   // 32 fp8 = f8f6f4 operand

__device__ __forceinline__ unsigned short f2bf(float f){
  unsigned u = __builtin_bit_cast(unsigned, f);
  u += 0x7fffu + ((u >> 16) & 1u);
  return (unsigned short)(u >> 16);
}

__device__ __forceinline__ float fsig(float a){
  return __builtin_amdgcn_rcpf(1.f + __builtin_amdgcn_exp2f(-1.44269504f * a));
}

// ---------------- emb fp32 -> bf16 table ----------------
__global__ void emb_cvt(const float* __restrict__ emb, unsigned short* __restrict__ out, int n4){
  int i = blockIdx.x * blockDim.x + threadIdx.x;
  if (i < n4){
    float4 v = *(const float4*)(emb + (size_t)i * 4);
    ushort4 o;
    o.x = f2bf(v.x); o.y = f2bf(v.y); o.z = f2bf(v.z); o.w = f2bf(v.w);
    *(ushort4*)(out + (size_t)i * 4) = o;
  }
}

// ---------------- persistent bidirectional GRU scan ----------------
// 256 blocks: 0..127 fwd, 128..255 bwd; 4 batch rows each (tile rows 0,4,8,12); 8 waves.
// xp (x@W+bias): bf16 MFMA, 4 timesteps packed per tile, woven 1 K-slice/step.
// recurrence (h@U): fp8 e4m3 via mfma_scale 16x16x128 (unit scales) -- one MFMA per gate.
__global__ __launch_bounds__(512, 2) void gru_scan(
    const int* __restrict__ tokens, const unsigned short* __restrict__ embb,
    const float* __restrict__ Wf, const float* __restrict__ Uf, const float* __restrict__ bfv,
    const float* __restrict__ Wb, const float* __restrict__ Ub, const float* __restrict__ bbv,
    float* __restrict__ hbuf)
{
  const int tid  = threadIdx.x;
  const int wid  = tid >> 6, lane = tid & 63;
  const int l15  = lane & 15, l4 = lane >> 4;
  const int dir  = blockIdx.x >> 7, grp = blockIdx.x & 127;
  const int cw   = wid * 16 + l15;                 // gate column in [0,128)

  const float* __restrict__ W  = dir ? Wb : Wf;
  const float* __restrict__ U  = dir ? Ub : Uf;
  const float* __restrict__ bv = dir ? bbv : bfv;

  // 96 KB -> 1 block/CU. Two fp8 h buffers (16 rows x 144B) at byte 0 and 4096.
  __shared__ __attribute__((aligned(16))) unsigned char hl[98304];

  // ---- bf16 xp B-frags: W only (K=128, 4 K-tiles) ----
  bvec8 Bz[4], Br[4], Bh[4];
#pragma unroll
  for (int kt = 0; kt < 4; ++kt){
#pragma unroll
    for (int j = 0; j < 8; ++j){
      const int k = kt * 32 + l4 * 8 + j;
      Bz[kt][j] = (short)f2bf(W[k * 384 + cw]);
      Br[kt][j] = (short)f2bf(W[k * 384 + 128 + cw]);
      Bh[kt][j] = (short)f2bf(W[k * 384 + 256 + cw]);
    }
  }

  // ---- fp8 recurrent B-frags: U, e4m3. lane(l4,l15): col=cw, k = l4*32 + byte_j ----
  ivec8 Qz, Qr, Qh;
#pragma unroll
  for (int w = 0; w < 8; ++w){
    const int k0 = l4 * 32 + w * 4;
    int vz = __builtin_amdgcn_cvt_pk_fp8_f32(U[(k0+0)*384 + cw], U[(k0+1)*384 + cw], 0, 0);
    vz     = __builtin_amdgcn_cvt_pk_fp8_f32(U[(k0+2)*384 + cw], U[(k0+3)*384 + cw], vz, 1);
    int vr = __builtin_amdgcn_cvt_pk_fp8_f32(U[(k0+0)*384 + 128 + cw], U[(k0+1)*384 + 128 + cw], 0, 0);
    vr     = __builtin_amdgcn_cvt_pk_fp8_f32(U[(k0+2)*384 + 128 + cw], U[(k0+3)*384 + 128 + cw], vr, 1);
    int vh = __builtin_amdgcn_cvt_pk_fp8_f32(U[(k0+0)*384 + 256 + cw], U[(k0+1)*384 + 256 + cw], 0, 0);
    vh     = __builtin_amdgcn_cvt_pk_fp8_f32(U[(k0+2)*384 + 256 + cw], U[(k0+3)*384 + 256 + cw], vh, 1);
    Qz[w] = vz; Qr[w] = vr; Qh[w] = vh;
  }

  // biases: z,r fully folded into xp accumulators; hh: input bias in xp, recurrent bias inside r*
  const float bzs = bv[cw] + bv[384 + cw];
  const float brs = bv[128 + cw] + bv[384 + 128 + cw];
  const float bix = bv[256 + cw];
  const float buh = bv[384 + 256 + cw];
  const fvec4 ZF  = {0.f, 0.f, 0.f, 0.f};

  for (int i = tid; i < 2048; i += 512) ((int*)hl)[i] = 0;   // zero both h buffers
  float h0 = 0.f;                                            // h[batch l4][cw] fp32 master

  // x gather: xp tile row = 4*batch + step_in_group
  const int  brow = l15 >> 2, srow = l15 & 3;
  const long tbx  = (long)(grp * 4 + brow) * TLEN;
  const int  tb0  = dir ? (TLEN - 1) : 0, tsg = dir ? -1 : 1;
  auto tix = [&](int t){ t = (t > TLEN - 1) ? (TLEN - 1) : t; return tb0 + tsg * t; };

  bvec8 xA[4], xB[4];
  fvec4 xZ = {bzs, bzs, bzs, bzs}, xR = {brs, brs, brs, brs}, xX = {bix, bix, bix, bix};
  fvec4 nZ, nR, nX;
  {
    const bvec8* p0 = (const bvec8*)(embb + (size_t)tokens[tbx + tix(srow)] * HD);
#pragma unroll
    for (int kt = 0; kt < 4; ++kt) xB[kt] = p0[kt * 4 + l4];
#pragma unroll
    for (int kt = 0; kt < 4; ++kt){
      xZ = __builtin_amdgcn_mfma_f32_16x16x32_bf16(xB[kt], Bz[kt], xZ, 0, 0, 0);
      xR = __builtin_amdgcn_mfma_f32_16x16x32_bf16(xB[kt], Br[kt], xR, 0, 0, 0);
      xX = __builtin_amdgcn_mfma_f32_16x16x32_bf16(xB[kt], Bh[kt], xX, 0, 0, 0);
    }
    const bvec8* p1 = (const bvec8*)(embb + (size_t)tokens[tbx + tix(4 + srow)] * HD);
#pragma unroll
    for (int kt = 0; kt < 4; ++kt) xA[kt] = p1[kt * 4 + l4];
  }
  int tok2 = tokens[tbx + tix(8 + srow)];
  nZ = (fvec4){bzs, bzs, bzs, bzs}; nR = (fvec4){brs, brs, brs, brs}; nX = (fvec4){bix, bix, bix, bix};

  const int hrd = l15 * 144 + l4 * 32;            // fp8 A-frag base (byte)
  const int wb  = (4 * l4) * 144 + cw;            // h write slot (byte)
  __syncthreads();

  // One step: 2x ds_read_b128 (fp8 h), weave 3 next-group xp bf16 MFMAs,
  // 3 scaled-fp8 K=128 MFMAs, gate on acc reg 0, 1-byte h write, one barrier.
#define STEP(S, P, XF) { \
    ivec4 alo = *(const ivec4*)&hl[(P) + hrd]; \
    ivec4 ahi = *(const ivec4*)&hl[(P) + hrd + 16]; \
    nZ = __builtin_amdgcn_mfma_f32_16x16x32_bf16(XF[S], Bz[S], nZ, 0, 0, 0); \
    nR = __builtin_amdgcn_mfma_f32_16x16x32_bf16(XF[S], Br[S], nR, 0, 0, 0); \
    nX = __builtin_amdgcn_mfma_f32_16x16x32_bf16(XF[S], Bh[S], nX, 0, 0, 0); \
    ivec8 af = __builtin_shufflevector(alo, ahi, 0, 1, 2, 3, 4, 5, 6, 7); \
    fvec4 aZ = __builtin_amdgcn_mfma_scale_f32_16x16x128_f8f6f4(af, Qz, ZF, 0, 0, 0, 0x7F7F7F7F, 0, 0x7F7F7F7F); \
    fvec4 aR = __builtin_amdgcn_mfma_scale_f32_16x16x128_f8f6f4(af, Qr, ZF, 0, 0, 0, 0x7F7F7F7F, 0, 0x7F7F7F7F); \
    fvec4 aU = __builtin_amdgcn_mfma_scale_f32_16x16x128_f8f6f4(af, Qh, ZF, 0, 0, 0, 0x7F7F7F7F, 0, 0x7F7F7F7F); \
    float zz = fsig(xZ[S] + aZ[0]); \
    float rg = fsig(xR[S] + aR[0]); \
    float ar = xX[S] + rg * (aU[0] + buh); ar = fmaxf(ar, -30.f); \
    float y  = __builtin_amdgcn_exp2f(-2.88539008f * ar); \
    float th = (1.f - y) * __builtin_amdgcn_rcpf(1.f + y); \
    h0 = th + zz * (h0 - th); \
    hl[((P) ^ 4096) + wb] = (unsigned char)(__builtin_amdgcn_cvt_pk_fp8_f32(h0, h0, 0, 0) & 0xff); \
    asm volatile("s_waitcnt lgkmcnt(0)" ::: "memory"); \
    __builtin_amdgcn_s_barrier(); \
  }

  for (int g = 0; g < 128; g += 2){
    {   // emb frags for group g+2 -> xB
      const bvec8* pn = (const bvec8*)(embb + (size_t)tok2 * HD);
#pragma unroll
      for (int kt = 0; kt < 4; ++kt) xB[kt] = pn[kt * 4 + l4];
      tok2 = tokens[tbx + tix(4 * (g + 3) + srow)];
    }
    STEP(0, 0, xA) STEP(1, 4096, xA) STEP(2, 0, xA) STEP(3, 4096, xA)
    xZ = nZ; xR = nR; xX = nX;
    nZ = (fvec4){bzs, bzs, bzs, bzs}; nR = (fvec4){brs, brs, brs, brs}; nX = (fvec4){bix, bix, bix, bix};
    {   // emb frags for group g+3 -> xA
      const bvec8* pn = (const bvec8*)(embb + (size_t)tok2 * HD);
#pragma unroll
      for (int kt = 0; kt < 4; ++kt) xA[kt] = pn[kt * 4 + l4];
      tok2 = tokens[tbx + tix(4 * (g + 4) + srow)];
    }
    STEP(0, 0, xB) STEP(1, 4096, xB) STEP(2, 0, xB) STEP(3, 4096, xB)
    xZ = nZ; xR = nR; xX = nX;
    nZ = (fvec4){bzs, bzs, bzs, bzs}; nR = (fvec4){brs, brs, brs, brs}; nX = (fvec4){bix, bix, bix, bix};
  }
#undef STEP

  // final state -> hbuf[512][256], fwd cols 0..127, bwd cols 128..255
  hbuf[(size_t)(grp * 4 + l4) * 256 + dir * 128 + cw] = h0;
}

// ---------------- head: sigmoid(hcat @ Wd + bd) ----------------
__global__ void head_k(const float* __restrict__ hbuf, const float* __restrict__ Wd,
                       const float* __restrict__ bd, float* __restrict__ out){
  const int wid = threadIdx.x >> 6, lane = threadIdx.x & 63;
  const int b = blockIdx.x * 4 + wid;
  const float* hr = hbuf + (size_t)b * 256;
  float s = 0.f;
#pragma unroll
  for (int j = 0; j < 4; ++j){ const int k = j * 64 + lane; s += hr[k] * Wd[k]; }
#pragma unroll
  for (int off = 32; off > 0; off >>= 1) s += __shfl_down(s, off);
  if (lane == 0) out[b] = 1.f / (1.f + __expf(-(s + bd[0])));
}

extern "C" void kernel_launch(void* const* d_in, const int* in_sizes, int n_in,
                              void* d_out, int out_size, void* d_ws, size_t ws_size,
                              hipStream_t stream){
  const int*   tokens = (const int*)  d_in[0];
  const float* emb    = (const float*)d_in[1];
  const float* Wf     = (const float*)d_in[2];
  const float* Uf     = (const float*)d_in[3];
  const float* bf_    = (const float*)d_in[4];
  const float* Wb     = (const float*)d_in[5];
  const float* Ub     = (const float*)d_in[6];
  const float* bb_    = (const float*)d_in[7];
  const float* Wd     = (const float*)d_in[8];
  const float* bd     = (const float*)d_in[9];
  float* out = (float*)d_out;

  unsigned short* embb = (unsigned short*)d_ws;                       // 12.8 MB bf16 table
  float* hbuf = (float*)((char*)d_ws + (size_t)VOC * HD * sizeof(unsigned short)); // 512 KB

  const int n4 = VOC * HD / 4;
  emb_cvt<<<(n4 + 255) / 256, 256, 0, stream>>>(emb, embb, n4);
  gru_scan<<<256, 512, 0, stream>>>(tokens, embb, Wf, Uf, bf_, Wb, Ub, bb_, hbuf);
  head_k<<<128, 256, 0, stream>>>(hbuf, Wd, bd, out);
}